// Round 2
// baseline (119.304 us; speedup 1.0000x reference)
//
#include <hip/hip_runtime.h>
#include <hip/hip_bf16.h>

// Problem constants
#define BATCH  16384
#define GATES  1023
#define NPAD   1024
#define OUTF   128

typedef unsigned short ushortT;
typedef short bf16x8 __attribute__((ext_vector_type(8)));
typedef float f32x4 __attribute__((ext_vector_type(4)));

__device__ inline float bf2f(ushortT u) {
    union { unsigned int i; float f; } v;
    v.i = ((unsigned int)u) << 16;
    return v.f;
}
__device__ inline ushortT f2bf(float f) {
    union { float f; unsigned int i; } v;
    v.f = f;
    unsigned int x = v.i;
    unsigned int r = (x + 0x7FFFu + ((x >> 16) & 1u)) >> 16;  // RNE
    return (ushortT)r;
}
// packed f32 pair -> bf16 pair (RNE); compiler lowers to v_cvt_pk_bf16_f32.
__device__ inline unsigned pkbf(float lo, float hi) {
    __hip_bfloat162 h = __float22bfloat162_rn(float2{lo, hi});
    union { __hip_bfloat162 h; unsigned u; } c;
    c.h = h;
    return c.u;
}
// Row-local sG swizzle: XOR ushort-index bits 3..5 with (row ^ row>>3)&7.
// Row-local (XOR span 128B < 2048B row stride) => leaf-overwrites-own-row
// in-place safety preserved; row>>3 term spreads the 4 quad-rows of the
// epilogue across distinct bank groups.
__device__ inline int swz8(int row) { return ((row ^ (row >> 3)) & 7) << 3; }

// async global->LDS, 16B/lane; lds base wave-uniform, HW writes base + lane*16.
__device__ inline void gl2lds16(const void* gptr, void* ldsptr) {
    __builtin_amdgcn_global_load_lds(
        (const __attribute__((address_space(1))) void*)gptr,
        (__attribute__((address_space(3))) void*)ldsptr, 16, 0, 0);
}

// ---------------- prep: gwT (tiled transpose+pad), zh, gbp ----------------
// blocks [0,64): gw (256x1023 f32) -> gwT (1024x256 bf16) via LDS 64x64 tiles
//   (coalesced reads along n, coalesced bf16x8 writes along k)
// blocks [64,128): z (128x1024 f32) -> zh bf16
// block 128: gbp
__global__ __launch_bounds__(256) void k_prep(const float* __restrict__ gw,
                                              const float* __restrict__ gb,
                                              const float* __restrict__ z,
                                              ushortT* __restrict__ gwT,
                                              float* __restrict__ gbp,
                                              ushortT* __restrict__ zh) {
    const int b = blockIdx.x, t = threadIdx.x;
    if (b < 64) {
        __shared__ ushortT tile[64][65];  // pad 65: transposed reads conflict-free
        const int k0 = (b >> 4) * 64, n0 = (b & 15) * 64;
        const int tr = t >> 6, tc = t & 63;  // wave tr handles k-row p*4+tr, cols tc
#pragma unroll
        for (int p = 0; p < 16; ++p) {
            int k = p * 4 + tr;
            int n = n0 + tc;
            float v = (n < GATES) ? gw[(size_t)(k0 + k) * GATES + n] : 0.f;
            tile[k][tc] = f2bf(v);
        }
        __syncthreads();
        // write gwT[n][k]: each thread 8 ushorts (16B) of one gwT row segment
#pragma unroll
        for (int p = 0; p < 2; ++p) {
            int nn = (t >> 3) + p * 32;
            int ks = (t & 7) * 8;
            ushortT o[8];
#pragma unroll
            for (int u = 0; u < 8; ++u) o[u] = tile[ks + u][nn];
            *(bf16x8*)(gwT + (size_t)(n0 + nn) * 256 + k0 + ks) = *(bf16x8*)o;
        }
    } else if (b < 128) {
        int i = (b - 64) * 256 + t;  // 16384 groups of 8 (131072 elems)
        const float4* p = (const float4*)z + (size_t)i * 2;
        float4 a = p[0], c = p[1];
        union { unsigned u[4]; bf16x8 v; } o;
        o.u[0] = pkbf(a.x, a.y); o.u[1] = pkbf(a.z, a.w);
        o.u[2] = pkbf(c.x, c.y); o.u[3] = pkbf(c.z, c.w);
        *(bf16x8*)(zh + (size_t)i * 8) = o.v;
    } else {
#pragma unroll
        for (int u = 0; u < 4; ++u) {
            int id = t * 4 + u;
            gbp[id] = (id < GATES) ? gb[id] : 0.f;
        }
    }
}

// ---------------- mega: x -> gatings -> leaves -> out, one block = 32 rows -----------
// LDS: sG 64KB row-major [row:32][idx:1024] bf16 with row-XOR swizzle (see swz8);
//      sS 16KB staging (two 8KB sub-chunks in m97 [row][32] layout).
// 80KB total -> 2 blocks/CU (8 waves/CU: barrier drain on one block overlaps
// the other block's MFMAs).
__global__ __launch_bounds__(256) void k_mega(const float* __restrict__ x,
                                              const ushortT* __restrict__ gwT,
                                              const float* __restrict__ gbp,
                                              const ushortT* __restrict__ zh,
                                              float* __restrict__ out) {
    __shared__ __align__(16) ushortT sG[32 * 1024];  // 64 KB
    __shared__ ushortT sS[8192];                     // 16 KB

    const int tid = threadIdx.x;
    const int wave = tid >> 6, lane = tid & 63;
    const int quad = lane >> 4, l15 = lane & 15;
    const int wr = wave >> 1, wc = wave & 1;   // 2x2 wave grid; wave tile 16x64
    const int bm = blockIdx.x * 32;
    const int lrow = lane >> 2;                // staging: row within 16-row group
    const int lcol = (lane & 3) * 8;           // staging: elem col within 32

    // ---- preload A: x rows (f32) -> bf16 MFMA fragments, af[c] covers k=c*32+quad*8
    bf16x8 af[8];
    {
        const float* xr = x + (size_t)(bm + wr * 16 + l15) * 256;
#pragma unroll
        for (int c = 0; c < 8; ++c) {
            const float4* p = (const float4*)(xr + c * 32 + quad * 8);
            float4 a = p[0], b = p[1];
            union { unsigned u[4]; bf16x8 v; } o;
            o.u[0] = pkbf(a.x, a.y); o.u[1] = pkbf(a.z, a.w);
            o.u[2] = pkbf(b.x, b.y); o.u[3] = pkbf(b.z, b.w);
            af[c] = o.v;
        }
    }

    // epilogue row constants (C/D: col=l15, row=quad*4+reg)
    const int row0 = wr * 16 + quad * 4;
    int eb[4], ex[4];
#pragma unroll
    for (int r = 0; r < 4; ++r) {
        eb[r] = (row0 + r) << 10;
        ex[r] = swz8(row0 + r);
    }

    // ---- P1: gatings = sigmoid(x @ gw + gb) for all 1024 cols, 32 rows ----
    for (int n0 = 0; n0 < 1024; n0 += 128) {
        f32x4 acc[4] = {};
        for (int k0 = 0; k0 < 256; k0 += 64) {
            // stage gwT rows [n0,n0+128) x k [k0,k0+64) -> sS (16 issues of 1KB)
#pragma unroll
            for (int r = 0; r < 4; ++r) {
                int q = wave * 4 + r, kc = q >> 3, e = q & 7;
                gl2lds16(gwT + (size_t)(n0 + e * 16 + lrow) * 256 + k0 + kc * 32 + lcol,
                         sS + kc * 4096 + e * 512);
            }
            __syncthreads();
#pragma unroll
            for (int ks = 0; ks < 2; ++ks) {
                bf16x8 a0 = af[(k0 >> 5) + ks];
#pragma unroll
                for (int j = 0; j < 4; ++j) {
                    bf16x8 b0 = *(const bf16x8*)(sS + ks * 4096 +
                                                 (wc * 64 + j * 16 + l15) * 32 + quad * 8);
                    acc[j] = __builtin_amdgcn_mfma_f32_16x16x32_bf16(a0, b0, acc[j], 0, 0, 0);
                }
            }
            __syncthreads();
        }
        // epilogue: sigmoid -> sG (swizzled row-major); pack pairs via cvt_pk
#pragma unroll
        for (int j = 0; j < 4; ++j) {
            int col = n0 + wc * 64 + j * 16 + l15;
            float bs = gbp[col];
            float g0 = 1.f / (1.f + __expf(-(acc[j][0] + bs)));
            float g1 = 1.f / (1.f + __expf(-(acc[j][1] + bs)));
            float g2 = 1.f / (1.f + __expf(-(acc[j][2] + bs)));
            float g3 = 1.f / (1.f + __expf(-(acc[j][3] + bs)));
            unsigned p0 = pkbf(g0, g1), p1 = pkbf(g2, g3);
            sG[eb[0] + (col ^ ex[0])] = (ushortT)p0;
            sG[eb[1] + (col ^ ex[1])] = (ushortT)(p0 >> 16);
            sG[eb[2] + (col ^ ex[2])] = (ushortT)p1;
            sG[eb[3] + (col ^ ex[3])] = (ushortT)(p1 >> 16);
        }
    }
    __syncthreads();

    // ---- P2: tree (all gating reads from LDS), leaves written in-place ----
    {
        const int r0 = wave * 8;
        for (int rr = 0; rr < 8; ++rr) {
            const int row = r0 + rr;
            const int rowb = row << 10;
            const int x8 = swz8(row);
            float P = 1.f;
#pragma unroll
            for (int d = 0; d < 6; ++d) {
                int idx = (1 << d) - 1 + (lane >> (6 - d));
                float g = bf2f(sG[rowb + (idx ^ x8)]);
                int bit = (lane >> (5 - d)) & 1;
                P *= bit ? (1.f - g) : g;
            }
            float v[16];
            v[0] = P;
#pragma unroll
            for (int d = 0; d < 4; ++d) {
                const int cnt = 1 << d;
                const int base = (1 << (d + 6)) - 1 + (lane << d);
#pragma unroll
                for (int t = 7; t >= 0; --t) {
                    if (t < cnt) {
                        int gi = base + t;
                        float g = bf2f(sG[rowb + (gi ^ x8)]);
                        float pv = v[t];
                        float a = pv * g;
                        v[2 * t] = a;
                        v[2 * t + 1] = pv - a;
                    }
                }
            }
            // pack 16 leaves -> 2x b128; leaves lane*16..+15 occupy exactly row
            // `row`'s own (swizzled, row-local) slots => in-place safe.
            union { unsigned u[4]; bf16x8 v; } q0, q1;
#pragma unroll
            for (int t = 0; t < 4; ++t) q0.u[t] = pkbf(v[2 * t], v[2 * t + 1]);
#pragma unroll
            for (int t = 0; t < 4; ++t) q1.u[t] = pkbf(v[8 + 2 * t], v[9 + 2 * t]);
            int a0 = rowb + ((lane << 4) ^ x8);
            *(bf16x8*)(sG + a0) = q0.v;
            *(bf16x8*)(sG + (a0 ^ 8)) = q1.v;
        }
    }
    __syncthreads();

    // ---- P3: out = leaf @ z^T (leaf from sG swizzled, z staged 16KB/iter) ----
    f32x4 acc[4] = {};
    const int rowA = wr * 16 + l15;
    const int baseA = rowA << 10;
    const int xA8 = swz8(rowA);
    for (int k0 = 0; k0 < 1024; k0 += 64) {
#pragma unroll
        for (int r = 0; r < 4; ++r) {
            int q = wave * 4 + r, kc = q >> 3, e = q & 7;
            gl2lds16(zh + (size_t)(e * 16 + lrow) * 1024 + k0 + kc * 32 + lcol,
                     sS + kc * 4096 + e * 512);
        }
        __syncthreads();
#pragma unroll
        for (int ks = 0; ks < 2; ++ks) {
            bf16x8 a0 = *(const bf16x8*)(sG + baseA + ((k0 + ks * 32 + quad * 8) ^ xA8));
#pragma unroll
            for (int j = 0; j < 4; ++j) {
                bf16x8 b0 = *(const bf16x8*)(sS + ks * 4096 +
                                             (wc * 64 + j * 16 + l15) * 32 + quad * 8);
                acc[j] = __builtin_amdgcn_mfma_f32_16x16x32_bf16(a0, b0, acc[j], 0, 0, 0);
            }
        }
        __syncthreads();
    }
    const int gm = bm + wr * 16 + quad * 4;
#pragma unroll
    for (int j = 0; j < 4; ++j) {
        int gn = wc * 64 + j * 16 + l15;
#pragma unroll
        for (int r = 0; r < 4; ++r)
            out[(size_t)(gm + r) * OUTF + gn] = acc[j][r];
    }
}

// ---------------- launch ----------------
extern "C" void kernel_launch(void* const* d_in, const int* in_sizes, int n_in,
                              void* d_out, int out_size, void* d_ws, size_t ws_size,
                              hipStream_t stream) {
    const float* x  = (const float*)d_in[0];   // 16384 x 256
    const float* gw = (const float*)d_in[1];   // 256 x 1023
    const float* gb = (const float*)d_in[2];   // 1023
    const float* z  = (const float*)d_in[3];   // 128 x 1024
    float* out = (float*)d_out;                // 16384 x 128

    char* ws = (char*)d_ws;
    ushortT* gwT = (ushortT*)(ws + 0);       // 524,288 B
    ushortT* zh  = (ushortT*)(ws + 524288);  // 262,144 B
    float*   gbp = (float*)  (ws + 786432);  //   4,096 B (total < 1 MB)

    k_prep<<<129, 256, 0, stream>>>(gw, gb, z, gwT, gbp, zh);
    k_mega<<<512, 256, 0, stream>>>(x, gwT, gbp, zh, out);
}